// Round 1
// baseline (2545.104 us; speedup 1.0000x reference)
//
#include <hip/hip_runtime.h>

// FPS (B=32, N=65536, S=512) + gather (C=64), fp32.
//
// Round-4: attack the 2.33 us/iter cross-block handshake (VALUBusy 29%, all
// pipes idle -> latency-bound on publish/poll round trips).
//  * Slot lines: per batch, TWO parity-alternated lines of 8 slots (64 B each,
//    one publisher per line -> no cross-XCD dirty-line clobber). Payload 32 B:
//    halfA = dwordx4 {pk.lo, pk.hi, cx, cy}, halfB = dwordx2 {cz, tag}.
//    pk = dist_bits<<32 | tag16<<16 | (0xFFFF^idx)  (u64 max == max dist,
//    min index on ties; tag bits identical across slots so order unaffected).
//    Both halves carry tag s+1 -> stale/mixed reads self-reject, so lines are
//    REUSED and stay hot in L2 (old scheme used a cold line per iteration).
//  * Publisher stores each half twice: sc0 sc1 (MALL always current -> sc1
//    readers always correct) then sc0 (line live in local XCD L2).
//  * Readers poll with sc0 (L2 hit ~250cy; the 8 blocks of a batch are
//    bx = b + 32*chunk, all == b mod 8 -> same XCD under round-robin
//    dispatch). Sticky per-wave demotion to sc0 sc1 after POLL_CAP failed
//    attempts keeps it deadlock-free if dispatch ever scatters the blocks.
//  * Winner coords ride in the slot; EVERY wave polls + reduces the 8 slots
//    itself (ballot/ffs + 3 shfl) -> no dependent centroid fetch, no LDS
//    cxyz broadcast, ONE __syncthreads per iteration.
//
// Bit-exactness: d = ((dx*dx + dy*dy) + dz*dz) via __fmul_rn/__fadd_rn (no
// fma contraction), fminf; pack preserves (max dist, first index) semantics.

#define BATCH 32
#define NPTS  65536
#define NSAMP 512
#define NCH   64
#define NBLK  8                      // blocks per batch
#define TPB   512
#define CHUNK (NPTS / NBLK)          // 8192
#define PPT   (CHUNK / TPB)          // 16
#define NWAVE (TPB / 64)             // 8
#define NITER (NSAMP - 1)            // 511
#define POLL_CAP 512

typedef unsigned int       u32;
typedef unsigned long long u64;
typedef __attribute__((ext_vector_type(4))) u32 u32x4;
typedef __attribute__((ext_vector_type(2))) u32 u32x2;

#define LINES_BYTES (BATCH * 2 * NBLK * 64)   // 32 KiB

__device__ __forceinline__ void slot_publish(u64 addr, u32x4 a, u32x2 b) {
    // sc1 pair first (MALL current -> demoted readers are always safe),
    // sc0 pair second (leaves the line live/dirty in the local XCD L2).
    // Same value both times -> any commit order is harmless.
    asm volatile(
        "global_store_dwordx4 %0, %1, off sc0 sc1\n\t"
        "global_store_dwordx2 %0, %2, off offset:16 sc0 sc1\n\t"
        "global_store_dwordx4 %0, %1, off sc0\n\t"
        "global_store_dwordx2 %0, %2, off offset:16 sc0"
        :: "v"(addr), "v"(a), "v"(b) : "memory");
}

__device__ __forceinline__ void slot_load(u64 addr, u32x4& a, u32x2& b,
                                          bool fast) {
    if (fast)
        asm volatile(
            "global_load_dwordx4 %0, %2, off sc0\n\t"
            "global_load_dwordx2 %1, %2, off offset:16 sc0\n\t"
            "s_waitcnt vmcnt(0)"
            : "=&v"(a), "=&v"(b) : "v"(addr) : "memory");
    else
        asm volatile(
            "global_load_dwordx4 %0, %2, off sc0 sc1\n\t"
            "global_load_dwordx2 %1, %2, off offset:16 sc0 sc1\n\t"
            "s_waitcnt vmcnt(0)"
            : "=&v"(a), "=&v"(b) : "v"(addr) : "memory");
}

__global__ __launch_bounds__(TPB, 1) void fps_kernel(
    const float* __restrict__ xyz,   // [B, N, 3]
    char* __restrict__ ws,           // slot lines, memset 0
    int* __restrict__ winners)       // [B, S]; winners[b][s] = idx[s+1]
{
    const int bx    = blockIdx.x;
    const int b     = bx & (BATCH - 1);
    const int chunk = bx >> 5;                 // 0..7
    const int tid   = threadIdx.x;
    const int lane  = tid & 63;
    const float* xb = xyz + (size_t)b * NPTS * 3;
    const int base  = chunk * CHUNK;

    float px[PPT], py[PPT], pz[PPT], dist[PPT];
#pragma unroll
    for (int i = 0; i < PPT; ++i) {
        int n = base + i * TPB + tid;
        const float* p = xb + (size_t)n * 3;
        px[i] = p[0]; py[i] = p[1]; pz[i] = p[2];
        dist[i] = 1e10f;
    }

    __shared__ u64 red[2][NWAVE];

    const u64 lines_b = (u64)(ws) + (u64)b * (2 * NBLK * 64);
    int* win_b = winners + b * NSAMP;

    float cx = xb[0], cy = xb[1], cz = xb[2];
    bool fast = true;                // sticky per-wave; demotes if sc0 stalls

    for (int s = 0; s < NITER; ++s) {          // 511 iters; idx[0]=0 implicit
        const u32 tag = (u32)(s + 1);

        // ---- dist update + per-thread first-index argmax ----
        float bv = -1.0f;
        int   bn = 0;
#pragma unroll
        for (int i = 0; i < PPT; ++i) {
            float dx = px[i] - cx;
            float dy = py[i] - cy;
            float dz = pz[i] - cz;
            float d  = __fadd_rn(__fadd_rn(__fmul_rn(dx, dx), __fmul_rn(dy, dy)),
                                 __fmul_rn(dz, dz));
            float nd = fminf(dist[i], d);
            dist[i] = nd;
            if (nd > bv) { bv = nd; bn = base + i * TPB + tid; }
        }

        // ---- pack + wave reduce (u64 max == max dist, min index) ----
        u64 pk = ((u64)__float_as_uint(bv) << 32)
               | (u64)((tag << 16) | (u32)(0xFFFF ^ bn));
#pragma unroll
        for (int off = 32; off >= 1; off >>= 1) {
            u64 o = __shfl_down(pk, off, 64);
            if (o > pk) pk = o;
        }
        if (lane == 0) red[s & 1][tid >> 6] = pk;
        __syncthreads();                       // the ONLY barrier per iter

        const u64 line = lines_b + (u64)((s & 1) * (NBLK * 64));

        // ---- wave 0: block reduce + publish (others fall through to poll) --
        if (tid < 64) {
            u64 bpk = red[s & 1][lane & 7];    // each octet holds all 8 waves
#pragma unroll
            for (int off = 4; off >= 1; off >>= 1) {
                u64 o = __shfl_xor(bpk, off, 64);
                if (o > bpk) bpk = o;
            }
            if (tid == 0) {
                int n = 0xFFFF ^ (u32)(bpk & 0xFFFF);
                const float* cp = xb + (size_t)n * 3;  // immutable -> cached
                u32x4 a; u32x2 bb;
                a.x = (u32)bpk;            a.y = (u32)(bpk >> 32);
                a.z = __float_as_uint(cp[0]); a.w = __float_as_uint(cp[1]);
                bb.x = __float_as_uint(cp[2]); bb.y = tag;
                slot_publish(line + (u64)chunk * 64, a, bb);
            }
        }

        // ---- ALL waves poll the 8 slots, self-validate via tags ----
        u32x4 A; u32x2 Bv;
        const u64 myaddr = line + (u64)((lane & 7) * 64);
        int tries = 0;
        for (;;) {
            slot_load(myaddr, A, Bv, fast);
            if (__all(((A.x >> 16) == tag) && (Bv.y == tag))) break;
            if (++tries >= POLL_CAP) fast = false;   // cross-XCD fallback
            __builtin_amdgcn_s_sleep(1);
        }

        // ---- per-wave winner reduce + coord broadcast (no 2nd barrier) ----
        u64 pkw = ((u64)A.y << 32) | A.x;
        u64 m = pkw;
#pragma unroll
        for (int off = 4; off >= 1; off >>= 1) {
            u64 o = __shfl_xor(m, off, 64);
            if (o > m) m = o;
        }
        int wl = __ffsll((u64)(__ballot(pkw == m) & 0xFFull)) - 1;
        cx = __uint_as_float(__shfl(A.z, wl, 64));
        cy = __uint_as_float(__shfl(A.w, wl, 64));
        cz = __uint_as_float(__shfl(Bv.x, wl, 64));
        if (chunk == 0 && tid == 0)
            win_b[s] = 0xFFFF ^ (u32)(m & 0xFFFF);   // idx[s+1]
    }
}

// idx[b][0] = 0; idx[b][s] = winners[b][s-1] for s >= 1.
__global__ __launch_bounds__(256) void gather_kernel(
    const float* __restrict__ xyz,   // [B, N, 3]
    const float* __restrict__ f,     // [B, N, C]
    const int* __restrict__ winners, // [B, S]
    float* __restrict__ out_xyz,     // [B, S, 3]
    float* __restrict__ out_f)       // [B, S, C]
{
    const int t  = threadIdx.x;
    const int g  = blockIdx.x * 4 + (t >> 6);
    const int ln = t & 63;
    const int b  = g >> 9;
    const int s  = g & (NSAMP - 1);

    int n = (s == 0) ? 0 : winners[b * NSAMP + (s - 1)];

    out_f[((size_t)b * NSAMP + s) * NCH + ln] = f[((size_t)b * NPTS + n) * NCH + ln];
    if (ln < 3)
        out_xyz[((size_t)b * NSAMP + s) * 3 + ln] =
            xyz[((size_t)b * NPTS + n) * 3 + ln];
}

extern "C" void kernel_launch(void* const* d_in, const int* in_sizes, int n_in,
                              void* d_out, int out_size, void* d_ws, size_t ws_size,
                              hipStream_t stream) {
    const float* xyz = (const float*)d_in[0];   // [32, 65536, 3]
    const float* f   = (const float*)d_in[1];   // [32, 65536, 64]
    float* out_xyz = (float*)d_out;                               // [32, 512, 3]
    float* out_f   = (float*)d_out + (size_t)BATCH * NSAMP * 3;   // [32, 512, 64]

    char* ws      = (char*)d_ws;                        // slot lines, 32 KiB
    int*  winners = (int*)((char*)d_ws + LINES_BYTES);  // [B, S]

    hipMemsetAsync(d_ws, 0, LINES_BYTES, stream);

    fps_kernel<<<BATCH * NBLK, TPB, 0, stream>>>(xyz, ws, winners);
    gather_kernel<<<BATCH * NSAMP / 4, 256, 0, stream>>>(xyz, f, winners,
                                                         out_xyz, out_f);
}

// Round 2
// 1787.107 us; speedup vs baseline: 1.4241x; 1.4241x over previous
//
#include <hip/hip_runtime.h>

// FPS (B=32, N=65536, S=512) + gather (C=64), fp32.
//
// Round-5: round-3 skeleton (wave-0-only publish/poll + LDS broadcast; that
// structure measured 2.33 us/iter) with the two isolated round-4 wins grafted
// on, minus the regressions:
//  * Hot tag-validated slot lines, parity-alternated (2 lines x 8 slots x 64B
//    per batch, reused): no cold-miss poll at the start of every iteration.
//    Payload 24B: halfA = dwordx4 {pk.lo, pk.hi, cx, cy}, halfB = {cz, tag}.
//    pk = dist_bits<<32 | tag<<16 | (0xFFFF^idx): u64 max == (max dist, min
//    idx on ties); tag bits identical across slots so ordering is unaffected;
//    both halves carry tag s+1 so stale/mixed reads self-reject. Parity makes
//    tag-exact matching ABA-safe (max inter-block skew is bounded by the
//    detect->publish dependency chain).
//  * Publisher fetches its OWN candidate's coords (own chunk, L2-warm) BEFORE
//    the store -- overlapped with other publishers -- instead of a dependent
//    global fetch of the global winner AFTER detection.
//  * ONE sc0 sc1 store pair (MALL is the coherence point; works regardless of
//    XCD placement). Wave 0 ONLY polls, with sc0 sc1 loads, no s_sleep:
//    256 polling waves x 24B per RTT cannot contend at MALL. (Round 4 proved
//    all-waves polling + double stores inflate RTT: 8x traffic, 4.0 us/iter.)
//
// Bit-exactness: d = ((dx*dx + dy*dy) + dz*dz) via __fmul_rn/__fadd_rn (no
// fma contraction), fminf; pack preserves (max dist, first index) semantics.

#define BATCH 32
#define NPTS  65536
#define NSAMP 512
#define NCH   64
#define NBLK  8                      // blocks per batch
#define TPB   512
#define CHUNK (NPTS / NBLK)          // 8192
#define PPT   (CHUNK / TPB)          // 16
#define NWAVE (TPB / 64)             // 8
#define NITER (NSAMP - 1)            // 511

typedef unsigned int       u32;
typedef unsigned long long u64;
typedef __attribute__((ext_vector_type(4))) u32 u32x4;
typedef __attribute__((ext_vector_type(2))) u32 u32x2;

#define LINES_BYTES (BATCH * 2 * NBLK * 64)   // 32 KiB

__device__ __forceinline__ void slot_publish(u64 addr, u32x4 a, u32x2 b) {
    asm volatile(
        "global_store_dwordx4 %0, %1, off sc0 sc1\n\t"
        "global_store_dwordx2 %0, %2, off offset:16 sc0 sc1"
        :: "v"(addr), "v"(a), "v"(b) : "memory");
}

__device__ __forceinline__ void slot_load(u64 addr, u32x4& a, u32x2& b) {
    asm volatile(
        "global_load_dwordx4 %0, %2, off sc0 sc1\n\t"
        "global_load_dwordx2 %1, %2, off offset:16 sc0 sc1\n\t"
        "s_waitcnt vmcnt(0)"
        : "=&v"(a), "=&v"(b) : "v"(addr) : "memory");
}

__global__ __launch_bounds__(TPB, 1) void fps_kernel(
    const float* __restrict__ xyz,   // [B, N, 3]
    char* __restrict__ ws,           // slot lines, memset 0
    int* __restrict__ winners)       // [B, S]; winners[b][s] = idx[s+1]
{
    const int bx    = blockIdx.x;
    const int b     = bx & (BATCH - 1);
    const int chunk = bx >> 5;                 // 0..7
    const int tid   = threadIdx.x;
    const int lane  = tid & 63;
    const float* xb = xyz + (size_t)b * NPTS * 3;
    const int base  = chunk * CHUNK;

    float px[PPT], py[PPT], pz[PPT], dist[PPT];
#pragma unroll
    for (int i = 0; i < PPT; ++i) {
        int n = base + i * TPB + tid;
        const float* p = xb + (size_t)n * 3;
        px[i] = p[0]; py[i] = p[1]; pz[i] = p[2];
        dist[i] = 1e10f;
    }

    __shared__ u64   red[NWAVE];
    __shared__ float cxyz[3];

    const u64 lines_b = (u64)(ws) + (u64)b * (2 * NBLK * 64);
    int* win_b = winners + b * NSAMP;

    float cx = xb[0], cy = xb[1], cz = xb[2];

    for (int s = 0; s < NITER; ++s) {          // 511 iters; idx[0]=0 implicit
        const u32 tag = (u32)(s + 1);

        // ---- dist update + per-thread first-index argmax ----
        float bv = -1.0f;
        int   bn = 0;
#pragma unroll
        for (int i = 0; i < PPT; ++i) {
            float dx = px[i] - cx;
            float dy = py[i] - cy;
            float dz = pz[i] - cz;
            float d  = __fadd_rn(__fadd_rn(__fmul_rn(dx, dx), __fmul_rn(dy, dy)),
                                 __fmul_rn(dz, dz));
            float nd = fminf(dist[i], d);
            dist[i] = nd;
            if (nd > bv) { bv = nd; bn = base + i * TPB + tid; }
        }

        // ---- pack + wave reduce (u64 max == max dist, min index) ----
        u64 pk = ((u64)__float_as_uint(bv) << 32)
               | (u64)((tag << 16) | (u32)(0xFFFF ^ bn));
#pragma unroll
        for (int off = 32; off >= 1; off >>= 1) {
            u64 o = __shfl_down(pk, off, 64);
            if (o > pk) pk = o;
        }
        if (lane == 0) red[tid >> 6] = pk;
        __syncthreads();

        const u64 line = lines_b + (u64)((s & 1) * (NBLK * 64));

        // ---- wave 0: block reduce, publish (coords from own chunk), poll --
        if (tid < 64) {
            u64 bpk = red[lane & 7];
#pragma unroll
            for (int off = 4; off >= 1; off >>= 1) {
                u64 o = __shfl_xor(bpk, off, 64);
                if (o > bpk) bpk = o;
            }
            if (lane == 0) {
                int n = 0xFFFF ^ (u32)(bpk & 0xFFFF);   // own-chunk candidate
                const float* cp = xb + (size_t)n * 3;   // immutable, L2-warm
                u32x4 a; u32x2 bb;
                a.x = (u32)bpk;               a.y = (u32)(bpk >> 32);
                a.z = __float_as_uint(cp[0]); a.w = __float_as_uint(cp[1]);
                bb.x = __float_as_uint(cp[2]); bb.y = tag;
                slot_publish(line + (u64)chunk * 64, a, bb);
            }

            // poll the 8 slots (lanes duplicate mod 8), tag-validated
            u32x4 A; u32x2 Bv;
            const u64 myaddr = line + (u64)(lane & 7) * 64;
            for (;;) {
                slot_load(myaddr, A, Bv);
                if (__all(((A.x >> 16) == tag) && (Bv.y == tag))) break;
            }

            // winner reduce over the 8 slots + coord pick
            u64 pkw = ((u64)A.y << 32) | A.x;
            u64 m = pkw;
#pragma unroll
            for (int off = 4; off >= 1; off >>= 1) {
                u64 o = __shfl_xor(m, off, 64);
                if (o > m) m = o;
            }
            int wl = __ffsll((u64)(__ballot(pkw == m) & 0xFFull)) - 1;
            u32 wx = __shfl(A.z, wl, 64);
            u32 wy = __shfl(A.w, wl, 64);
            u32 wz = __shfl(Bv.x, wl, 64);
            if (lane == 0) {
                cxyz[0] = __uint_as_float(wx);
                cxyz[1] = __uint_as_float(wy);
                cxyz[2] = __uint_as_float(wz);
                if (chunk == 0)
                    win_b[s] = 0xFFFF ^ (u32)(m & 0xFFFF);   // idx[s+1]
            }
        }
        __syncthreads();
        cx = cxyz[0]; cy = cxyz[1]; cz = cxyz[2];
    }
}

// idx[b][0] = 0; idx[b][s] = winners[b][s-1] for s >= 1.
__global__ __launch_bounds__(256) void gather_kernel(
    const float* __restrict__ xyz,   // [B, N, 3]
    const float* __restrict__ f,     // [B, N, C]
    const int* __restrict__ winners, // [B, S]
    float* __restrict__ out_xyz,     // [B, S, 3]
    float* __restrict__ out_f)       // [B, S, C]
{
    const int t  = threadIdx.x;
    const int g  = blockIdx.x * 4 + (t >> 6);
    const int ln = t & 63;
    const int b  = g >> 9;
    const int s  = g & (NSAMP - 1);

    int n = (s == 0) ? 0 : winners[b * NSAMP + (s - 1)];

    out_f[((size_t)b * NSAMP + s) * NCH + ln] = f[((size_t)b * NPTS + n) * NCH + ln];
    if (ln < 3)
        out_xyz[((size_t)b * NSAMP + s) * 3 + ln] =
            xyz[((size_t)b * NPTS + n) * 3 + ln];
}

extern "C" void kernel_launch(void* const* d_in, const int* in_sizes, int n_in,
                              void* d_out, int out_size, void* d_ws, size_t ws_size,
                              hipStream_t stream) {
    const float* xyz = (const float*)d_in[0];   // [32, 65536, 3]
    const float* f   = (const float*)d_in[1];   // [32, 65536, 64]
    float* out_xyz = (float*)d_out;                               // [32, 512, 3]
    float* out_f   = (float*)d_out + (size_t)BATCH * NSAMP * 3;   // [32, 512, 64]

    char* ws      = (char*)d_ws;                        // slot lines, 32 KiB
    int*  winners = (int*)((char*)d_ws + LINES_BYTES);  // [B, S]

    hipMemsetAsync(d_ws, 0, LINES_BYTES, stream);

    fps_kernel<<<BATCH * NBLK, TPB, 0, stream>>>(xyz, ws, winners);
    gather_kernel<<<BATCH * NSAMP / 4, 256, 0, stream>>>(xyz, f, winners,
                                                         out_xyz, out_f);
}